// Round 6
// baseline (243.035 us; speedup 1.0000x reference)
//
#include <hip/hip_runtime.h>
#include <hip/hip_fp16.h>
#include <math.h>

#define NN 50000
#define E0 800000
#define ET 850000
#define NBK 196  // CSR buckets = ceil(NN/256), 256 nodes each
#define TILE 4096
#define NTILES 208  // ceil(ET/TILE)
#define CAP 8192    // per-bucket region (packed & padded csr)

typedef unsigned int uint32;
typedef unsigned short u16;
typedef __attribute__((ext_vector_type(8))) _Float16 f16x8;  // 8 f16 = 4 VGPRs
typedef __attribute__((ext_vector_type(4))) float f32x4;

__device__ __forceinline__ u16 f2h(float f) {
  return __half_as_ushort(__float2half(f));  // RNE
}
__device__ __forceinline__ float h2f(u16 u) {
  return __half2float(__ushort_as_half(u));
}

// 256-thread inclusive scan: wave-shuffle (no barriers) + 4-entry wave combine.
__device__ __forceinline__ int block_incl_scan(int v, int tid, int* wsum) {
  const int lane = tid & 63, wid = tid >> 6;
  int val = v;
#pragma unroll
  for (int off = 1; off < 64; off <<= 1) {
    int t = __shfl_up(val, off);
    if (lane >= off) val += t;
  }
  if (lane == 63) wsum[wid] = val;
  __syncthreads();
  int wofs = 0;
#pragma unroll
  for (int w = 0; w < 4; ++w) wofs += (w < wid) ? wsum[w] : 0;
  return val + wofs;
}

// ---- fused: CSR partition (blocks 0..NTILES-1) + W/lw transposes (3 blocks) ----
// Edge loads vectorized int4: E0 and ET are multiples of 4 -> 4-edge chunks are
// uniformly normal / self-loop / invalid (no straddle cases).
__global__ __launch_bounds__(256) void partition_prep_kernel(
    const int* __restrict__ ei, int* __restrict__ gcursor, uint32* __restrict__ packed,
    const float* __restrict__ W0, const float* __restrict__ W1,
    const float* __restrict__ lw,
    u16* __restrict__ w0t, u16* __restrict__ w1t, u16* __restrict__ lwt)
{
  __shared__ __align__(16) char smem[23872];
  const int b = blockIdx.x;
  const int tid = threadIdx.x;
  if (b < NTILES) {
    int* hist  = (int*)smem;               // 1024 (256 ints)
    int* scanb = (int*)(smem + 1024);      // 1024
    int* gofs  = (int*)(smem + 2048);      // 1024
    int* wsum  = (int*)(smem + 3072);      // 16
    uint32* shuf = (uint32*)(smem + 3088); // 16384
    unsigned char* sbkt = (unsigned char*)(smem + 19472);  // 4096
    const int t0 = b * TILE;
    hist[tid] = 0;
    __syncthreads();
    int myb[16]; int myr[16]; uint32 mypk[16];
#pragma unroll
    for (int it = 0; it < 4; ++it) {
      const int q = it * 256 + tid;   // 4-edge chunk index within tile
      const int e4 = t0 + q * 4;      // first edge of chunk (multiple of 4)
      const bool valid = (e4 < ET);
      int sa[4], da[4];
      if (valid) {
        if (e4 + 3 < E0) {   // entirely normal edges (clean split: E0 % 4 == 0)
          int4 sv = *(const int4*)&ei[e4];
          int4 dv = *(const int4*)&ei[E0 + e4];
          sa[0] = sv.x; sa[1] = sv.y; sa[2] = sv.z; sa[3] = sv.w;
          da[0] = dv.x; da[1] = dv.y; da[2] = dv.z; da[3] = dv.w;
        } else {             // entirely self-loops (ET % 4 == 0 -> no partial tail)
#pragma unroll
          for (int u = 0; u < 4; ++u) { sa[u] = e4 - E0 + u; da[u] = sa[u]; }
        }
      }
#pragma unroll
      for (int u = 0; u < 4; ++u) {
        const int i = it * 4 + u;
        myb[i] = -1;
        if (valid) {
          const int src = sa[u], dst = da[u];
          myb[i] = dst >> 8;
          mypk[i] = ((uint32)(dst & 255) << 16) | (uint32)src;
          myr[i] = atomicAdd(&hist[myb[i]], 1);
        }
      }
    }
    __syncthreads();
    const int v = (tid < NBK) ? hist[tid] : 0;
    const int incl = block_incl_scan(v, tid, wsum);
    if (tid < NBK) {
      scanb[tid] = incl - v;
      gofs[tid] = (v > 0) ? atomicAdd(&gcursor[tid], v) : 0;
    }
    __syncthreads();
#pragma unroll
    for (int i = 0; i < 16; ++i) {
      if (myb[i] >= 0) {
        int slot = scanb[myb[i]] + myr[i];
        shuf[slot] = mypk[i];
        sbkt[slot] = (unsigned char)myb[i];
      }
    }
    __syncthreads();
    const int tcount = (t0 + TILE <= ET) ? TILE : (ET - t0);
    for (int i = tid; i < tcount; i += 256) {
      int bb = sbkt[i];
      packed[(size_t)bb * CAP + gofs[bb] + (i - scanb[bb])] = shuf[i];
    }
  } else if (b < NTILES + 2) {
    const float* W = (b == NTILES) ? W0 : W1;
    u16* Wt = (b == NTILES) ? w0t : w1t;
    float (*tile)[129] = (float(*)[129])smem;   // 16.5 KB overlay
    for (int k0 = 0; k0 < 128; k0 += 32) {
      __syncthreads();
#pragma unroll
      for (int it = 0; it < 4; ++it) {
        int q = tid + it * 256;
        int kk = q >> 5, n4 = (q & 31) * 4;
        float4 v = *(const float4*)&W[(k0 + kk) * 128 + n4];
        tile[kk][n4 + 0] = v.x; tile[kk][n4 + 1] = v.y;
        tile[kk][n4 + 2] = v.z; tile[kk][n4 + 3] = v.w;
      }
      __syncthreads();
      int n = tid >> 1, h = (tid & 1) * 16;
      __align__(16) u16 tmp[16];
#pragma unroll
      for (int j = 0; j < 16; ++j) tmp[j] = f2h(tile[h + j][n]);
      *(uint4*)&Wt[n * 128 + k0 + h] = *(uint4*)&tmp[0];
      *(uint4*)&Wt[n * 128 + k0 + h + 8] = *(uint4*)&tmp[8];
    }
  } else {
    for (int idx = tid; idx < 48 * 256; idx += 256) {
      int j = idx >> 8, k = idx & 255;
      lwt[idx] = (j < 40) ? f2h(lw[k * 40 + j]) : (u16)0;
    }
  }
}

// Pass 2 body: per bucket, padded local CSR in LDS (sentinel = NN), u16 csr,
// packed-u32 coalesced writes. Fused into layer-1 gemm dispatch (independent work).
__device__ __forceinline__ void build_body(
    char* smem, int b,
    const uint32* __restrict__ packed, const int* __restrict__ gcursor,
    int2* __restrict__ rowinfo, u16* __restrict__ csr_src)
{
  int* h      = (int*)smem;            // 1024
  int* sc     = (int*)(smem + 1024);   // 1024
  int* cur    = (int*)(smem + 2048);   // 1024
  int* wsum   = (int*)(smem + 3072);   // 16
  int* ptot_p = (int*)(smem + 3088);   // 16 (pad)
  u16* simg   = (u16*)(smem + 3104);   // 16384
  const int tid = threadIdx.x;
  const int cnt = gcursor[b];
  const uint32* pk = packed + (size_t)b * CAP;
  h[tid] = 0;
  cur[tid] = 0;
  __syncthreads();
  for (int i = tid; i < cnt; i += 256) atomicAdd(&h[(pk[i] >> 16) & 255], 1);
  __syncthreads();
  const int pd = (h[tid] + 7) & ~7;   // pad to multiple of 8
  const int incl = block_incl_scan(pd, tid, wsum);
  sc[tid] = incl - pd;
  if (tid == 255) *ptot_p = incl;
  __syncthreads();
  const int ptot = *ptot_p;
  for (int i = tid; i < ptot; i += 256) simg[i] = (u16)NN;   // sentinel fill
  __syncthreads();
  for (int i = tid; i < cnt; i += 256) {
    uint32 p = pk[i];
    int dl = (p >> 16) & 255;
    int r = atomicAdd(&cur[dl], 1);
    simg[sc[dl] + r] = (u16)(p & 0xFFFFu);
  }
  __syncthreads();
  int n = b * 256 + tid;
  if (n < NN) rowinfo[n] = make_int2(b * CAP + sc[tid], pd);
  // ptot is a multiple of 8 -> pair-packed u32 stores cover it exactly
  uint32* dst = (uint32*)(csr_src + (size_t)b * CAP);
  const uint32* sim32 = (const uint32*)simg;
  for (int i = tid; i < (ptot >> 1); i += 256) dst[i] = sim32[i];
}

// ---------------- MFMA GEMM (X @ W) + attention logits, f16 ----------------
__global__ __launch_bounds__(256) void gemm_att_kernel(
    const float* __restrict__ Xf, const u16* __restrict__ Xh,
    const u16* __restrict__ Wt,
    const float* __restrict__ avs, const float* __restrict__ avd,
    u16* __restrict__ hfeat, float* __restrict__ es, float* __restrict__ ed,
    int nnodes,
    const uint32* __restrict__ packed, const int* __restrict__ gcursor,
    int2* __restrict__ rowinfo, u16* __restrict__ csr_src)
{
  __shared__ __align__(16) char smem[20608];  // max(gemm 18944, build 19488)
  const int ngemm = (nnodes + 63) >> 6;
  if ((int)blockIdx.x >= ngemm) {
    build_body(smem, (int)blockIdx.x - ngemm, packed, gcursor, rowinfo, csr_src);
    return;
  }
  u16* hout   = (u16*)smem;                 // 64*136*2 = 17408
  float* es_s = (float*)(smem + 17408);     // [2][64] = 512
  float* ed_s = (float*)(smem + 17920);     // [2][64] = 512
  const int tid = threadIdx.x;
  const int wid = tid >> 6, lane = tid & 63;
  const int quad = lane >> 4, lc = lane & 15;
  const int n0 = blockIdx.x * 64;
  if (blockIdx.x == 0 && tid < 2) es[2 * NN + tid] = -1e30f;  // sentinel logits -> w=0

  const int arow = wid * 16 + lc;
  const int rrow = min(n0 + arow, nnodes - 1);  // clamp tail (output guarded)

  f32x4 acc[8];
#pragma unroll
  for (int t = 0; t < 8; ++t) acc[t] = (f32x4){0.f, 0.f, 0.f, 0.f};
#pragma unroll
  for (int ks = 0; ks < 4; ++ks) {
    const int k0 = ks * 32 + quad * 8;
    f16x8 a;
    if (Xf) {
      const float4* xr = (const float4*)&Xf[(size_t)rrow * 128 + k0];
      float4 v0 = xr[0], v1 = xr[1];
      a[0] = (_Float16)v0.x; a[1] = (_Float16)v0.y;
      a[2] = (_Float16)v0.z; a[3] = (_Float16)v0.w;
      a[4] = (_Float16)v1.x; a[5] = (_Float16)v1.y;
      a[6] = (_Float16)v1.z; a[7] = (_Float16)v1.w;
    } else {
      a = *(const f16x8*)&Xh[(size_t)rrow * 128 + k0];
    }
#pragma unroll
    for (int t = 0; t < 8; ++t) {
      f16x8 bfr = *(const f16x8*)&Wt[(t * 16 + lc) * 128 + k0];  // L2-resident
      acc[t] = __builtin_amdgcn_mfma_f32_16x16x32_f16(a, bfr, acc[t], 0, 0, 0);
    }
  }

  // attention partials: quad-local shuffle reduction (single writer, no atomics)
  float av_s[8], av_d[8];
#pragma unroll
  for (int t = 0; t < 8; ++t) { av_s[t] = avs[t * 16 + lc]; av_d[t] = avd[t * 16 + lc]; }
#pragma unroll
  for (int r = 0; r < 4; ++r) {
    float s0 = 0.f, s1 = 0.f, d0 = 0.f, d1 = 0.f;
#pragma unroll
    for (int t = 0; t < 4; ++t) { s0 += acc[t][r] * av_s[t]; d0 += acc[t][r] * av_d[t]; }
#pragma unroll
    for (int t = 4; t < 8; ++t) { s1 += acc[t][r] * av_s[t]; d1 += acc[t][r] * av_d[t]; }
#pragma unroll
    for (int m = 1; m < 16; m <<= 1) {
      s0 += __shfl_xor(s0, m); s1 += __shfl_xor(s1, m);
      d0 += __shfl_xor(d0, m); d1 += __shfl_xor(d1, m);
    }
    if (lc == 0) {
      int row = wid * 16 + quad * 4 + r;
      es_s[row] = s0; es_s[64 + row] = s1;
      ed_s[row] = d0; ed_s[64 + row] = d1;
    }
  }
  // f16 output roundtrip for coalesced writeback
#pragma unroll
  for (int t = 0; t < 8; ++t)
#pragma unroll
    for (int r = 0; r < 4; ++r)
      hout[(wid * 16 + quad * 4 + r) * 136 + t * 16 + lc] = f2h(acc[t][r]);
  __syncthreads();
#pragma unroll
  for (int it = 0; it < 4; ++it) {
    int g = tid + it * 256;
    int r = g >> 4, c8 = (g & 15) * 8;
    if (n0 + r < nnodes)
      *(uint4*)&hfeat[(size_t)(n0 + r) * 128 + c8] = *(const uint4*)&hout[r * 136 + c8];
  }
  if (tid < 64) {
    int n = n0 + tid;
    if (n < nnodes) {
      es[n * 2 + 0] = es_s[tid];      es[n * 2 + 1] = es_s[64 + tid];
      ed[n * 2 + 0] = ed_s[tid];      ed[n * 2 + 1] = ed_s[64 + tid];
    }
  }
}

// ---------------- aggregation: one wave per node, 8 edges/iter ----------------
// 256-thread blocks (4 waves) -- R4 showed 1024-thd blocks quantize occupancy
// down. Deep pipeline: chunk c+1 indices/weights/rows issued before consuming c.
// HEAD=true (layer 2): instead of writing the h2 row, compute the classifier
// head + log_softmax in-registers and write the final output. After the
// xor(16)/xor(32) reduce, ALL 64 lanes hold the full h2 row slice for their fl,
// so the [h1|h2] @ lw dot distributes as: lane (eg,fl) accumulates 10 logits
// (j = eg*10..eg*10+9) over its 16 k's, fl-group shuffle-reduce, wave softmax.
// Numerics match the old final_kernel: h1/h2 inputs f16-rounded, f32 accum.
template <bool HEAD>
__global__ __launch_bounds__(256) void aggregate_kernel(
    const uint4* __restrict__ hfeat4, const float* __restrict__ es, const float* __restrict__ ed,
    const int2* __restrict__ rowinfo, const u16* __restrict__ csr_src,
    const float* __restrict__ bias, u16* __restrict__ out, int nnodes,
    const uint4* __restrict__ h1b4, const u16* __restrict__ lwt,
    const float* __restrict__ lb, float* __restrict__ logits)
{
  int n = (blockIdx.x * blockDim.x + threadIdx.x) >> 6;
  int lane = threadIdx.x & 63;
  if (n >= nnodes) return;
  const int eg = lane >> 4;
  const int fl = lane & 15;
  const int hd = (fl >= 8) ? 1 : 0;
  const int2 ri = rowinfo[n];
  const int nch = ri.y >> 3;
  const int j0 = ri.x + eg;
  const float edn = ed[n * 2 + hd];

  float acc[8];
#pragma unroll
  for (int t = 0; t < 8; ++t) acc[t] = 0.f;
  float den = 0.f;

  // prologue: chunk 0 indices, weights, feature rows
  int iA0 = csr_src[j0], iA1 = csr_src[j0 + 4];
  float e0 = es[iA0 * 2 + hd] + edn; e0 = fmaxf(e0, 0.2f * e0);
  float e1 = es[iA1 * 2 + hd] + edn; e1 = fmaxf(e1, 0.2f * e1);
  float wA0 = __expf(e0), wA1 = __expf(e1);
  uint4 hA0 = hfeat4[(size_t)iA0 * 16 + fl];
  uint4 hA1 = hfeat4[(size_t)iA1 * 16 + fl];

  for (int c = 0;;) {
    const bool more = (c + 1 < nch);
    float wB0 = 0.f, wB1 = 0.f; uint4 hB0, hB1;
    if (more) {
      const int jb = j0 + (c + 1) * 8;
      int iB0 = csr_src[jb], iB1 = csr_src[jb + 4];
      float f0 = es[iB0 * 2 + hd] + edn; f0 = fmaxf(f0, 0.2f * f0);
      float f1 = es[iB1 * 2 + hd] + edn; f1 = fmaxf(f1, 0.2f * f1);
      wB0 = __expf(f0); wB1 = __expf(f1);
      hB0 = hfeat4[(size_t)iB0 * 16 + fl];   // issued before consuming hA*
      hB1 = hfeat4[(size_t)iB1 * 16 + fl];
    }
    // f16 unpack folds into v_fma_mix_f32 (fp32 acc, f16 src via op_sel)
    acc[0] = fmaf(wA0, h2f((u16)(hA0.x & 0xFFFFu)), acc[0]);
    acc[1] = fmaf(wA0, h2f((u16)(hA0.x >> 16)),     acc[1]);
    acc[2] = fmaf(wA0, h2f((u16)(hA0.y & 0xFFFFu)), acc[2]);
    acc[3] = fmaf(wA0, h2f((u16)(hA0.y >> 16)),     acc[3]);
    acc[4] = fmaf(wA0, h2f((u16)(hA0.z & 0xFFFFu)), acc[4]);
    acc[5] = fmaf(wA0, h2f((u16)(hA0.z >> 16)),     acc[5]);
    acc[6] = fmaf(wA0, h2f((u16)(hA0.w & 0xFFFFu)), acc[6]);
    acc[7] = fmaf(wA0, h2f((u16)(hA0.w >> 16)),     acc[7]);
    acc[0] = fmaf(wA1, h2f((u16)(hA1.x & 0xFFFFu)), acc[0]);
    acc[1] = fmaf(wA1, h2f((u16)(hA1.x >> 16)),     acc[1]);
    acc[2] = fmaf(wA1, h2f((u16)(hA1.y & 0xFFFFu)), acc[2]);
    acc[3] = fmaf(wA1, h2f((u16)(hA1.y >> 16)),     acc[3]);
    acc[4] = fmaf(wA1, h2f((u16)(hA1.z & 0xFFFFu)), acc[4]);
    acc[5] = fmaf(wA1, h2f((u16)(hA1.z >> 16)),     acc[5]);
    acc[6] = fmaf(wA1, h2f((u16)(hA1.w & 0xFFFFu)), acc[6]);
    acc[7] = fmaf(wA1, h2f((u16)(hA1.w >> 16)),     acc[7]);
    den += wA0 + wA1;
    if (!more) break;
    wA0 = wB0; wA1 = wB1; hA0 = hB0; hA1 = hB1;
    ++c;
  }

#pragma unroll
  for (int t = 0; t < 8; ++t) {
    acc[t] += __shfl_xor(acc[t], 16);
    acc[t] += __shfl_xor(acc[t], 32);
  }
  den += __shfl_xor(den, 16);
  den += __shfl_xor(den, 32);

  // epilogue constants (all lanes hold the full reduced row slice for their fl)
  float inv = 1.f / den;
  float4 b0 = *(const float4*)&bias[fl * 8];
  float4 b1 = *(const float4*)&bias[fl * 8 + 4];
  float bv[8] = {b0.x, b0.y, b0.z, b0.w, b1.x, b1.y, b1.z, b1.w};
  u16 pk[8];
#pragma unroll
  for (int t = 0; t < 8; ++t) {
    float v = acc[t] * inv + bv[t];
    v = (v > 0.f) ? v : (__expf(v) - 1.f);  // ELU
    pk[t] = f2h(v);
  }

  if (!HEAD) {
    if (eg == 0) {
      uint4 o;
      o.x = (uint32)pk[0] | ((uint32)pk[1] << 16);
      o.y = (uint32)pk[2] | ((uint32)pk[3] << 16);
      o.z = (uint32)pk[4] | ((uint32)pk[5] << 16);
      o.w = (uint32)pk[6] | ((uint32)pk[7] << 16);
      ((uint4*)out)[(size_t)n * 16 + fl] = o;
    }
    return;
  }

  // ---- fused classifier head + log_softmax (replaces final_kernel) ----
  // f16-rounded h2 (same values old final read from h2b) and h1 row from h1b.
  float h2v[8], h1v[8];
#pragma unroll
  for (int t = 0; t < 8; ++t) h2v[t] = h2f(pk[t]);
  {
    uint4 h1r = h1b4[(size_t)n * 16 + fl];  // broadcast across eg, L2-hot
    h1v[0] = h2f((u16)(h1r.x & 0xFFFFu)); h1v[1] = h2f((u16)(h1r.x >> 16));
    h1v[2] = h2f((u16)(h1r.y & 0xFFFFu)); h1v[3] = h2f((u16)(h1r.y >> 16));
    h1v[4] = h2f((u16)(h1r.z & 0xFFFFu)); h1v[5] = h2f((u16)(h1r.z >> 16));
    h1v[6] = h2f((u16)(h1r.w & 0xFFFFu)); h1v[7] = h2f((u16)(h1r.w >> 16));
  }
  float lg[10];
#pragma unroll
  for (int jj = 0; jj < 10; ++jj) {
    const int j = eg * 10 + jj;
    const f16x8 wa = *(const f16x8*)&lwt[j * 256 + fl * 8];        // h1 cols (L1)
    const f16x8 wb = *(const f16x8*)&lwt[j * 256 + 128 + fl * 8];  // h2 cols
    float p = 0.f;
#pragma unroll
    for (int t = 0; t < 8; ++t) p = fmaf(h1v[t], (float)wa[t], p);
#pragma unroll
    for (int t = 0; t < 8; ++t) p = fmaf(h2v[t], (float)wb[t], p);
    lg[jj] = p;
  }
  // reduce over fl (16 lanes) for each of the 10 logits
#pragma unroll
  for (int m = 1; m < 16; m <<= 1)
#pragma unroll
    for (int jj = 0; jj < 10; ++jj) lg[jj] += __shfl_xor(lg[jj], m);
  // bias + max
  float mx = -INFINITY;
#pragma unroll
  for (int jj = 0; jj < 10; ++jj) {
    lg[jj] += lb[eg * 10 + jj];
    mx = fmaxf(mx, lg[jj]);
  }
  mx = fmaxf(mx, __shfl_xor(mx, 16));
  mx = fmaxf(mx, __shfl_xor(mx, 32));
  float s = 0.f;
#pragma unroll
  for (int jj = 0; jj < 10; ++jj) s += __expf(lg[jj] - mx);
  s += __shfl_xor(s, 16);   // eg-group values duplicated across fl -> sums across eg
  s += __shfl_xor(s, 32);
  const float lgs = mx + __logf(s);
  if (fl < 10) {
    // static-index select of lg[fl] (runtime index would spill to scratch)
    float wv = lg[0];
#pragma unroll
    for (int jj = 1; jj < 10; ++jj) wv = (fl == jj) ? lg[jj] : wv;
    logits[(size_t)n * 40 + eg * 10 + fl] = wv - lgs;
  }
}

// ---------------- launch ----------------

extern "C" void kernel_launch(void* const* d_in, const int* in_sizes, int n_in,
                              void* d_out, int out_size, void* d_ws, size_t ws_size,
                              hipStream_t stream) {
  const float* x   = (const float*)d_in[0];
  const int*   ei  = (const int*)d_in[1];
  const float* W0  = (const float*)d_in[2];
  const float* as0 = (const float*)d_in[3];
  const float* ad0 = (const float*)d_in[4];
  const float* b0  = (const float*)d_in[5];
  const float* W1  = (const float*)d_in[6];
  const float* as1 = (const float*)d_in[7];
  const float* ad1 = (const float*)d_in[8];
  const float* b1  = (const float*)d_in[9];
  const float* lw  = (const float*)d_in[10];
  const float* lb  = (const float*)d_in[11];
  float* out = (float*)d_out;

  char* p = (char*)d_ws;
  auto carve = [&](size_t bytes) { char* r = p; p += (bytes + 255) & ~(size_t)255; return r; };
  u16* w0t    = (u16*)carve(128 * 128 * 2);
  u16* w1t    = (u16*)carve(128 * 128 * 2);
  u16* lwt    = (u16*)carve(48 * 256 * 2);
  u16* hfeat  = (u16*)carve((size_t)(NN + 1) * 128 * 2);  // +1 sentinel row
  u16* h1b    = (u16*)carve((size_t)NN * 128 * 2);
  float* es   = (float*)carve((size_t)(NN + 1) * 2 * 4);  // +sentinel logits
  float* ed   = (float*)carve((size_t)NN * 2 * 4);
  int2* rowinfo = (int2*)carve((size_t)NN * 8);
  u16* csr    = (u16*)carve((size_t)NBK * CAP * 2);       // u16 node ids (NN < 65536)
  uint32* packed = (uint32*)carve((size_t)NBK * CAP * 4);
  int* gcursor = (int*)carve(NBK * 4);

  hipMemsetAsync(gcursor, 0, NBK * 4, stream);

  const int NG = (NN + 63) / 64;  // 782

  // CSR partition + weight transposes (211 blocks)
  partition_prep_kernel<<<NTILES + 3, 256, 0, stream>>>(
      ei, gcursor, packed, W0, W1, lw, w0t, w1t, lwt);

  // layer 1: gemm (f32 input, in-register f16 convert) + fused CSR build blocks
  gemm_att_kernel<<<NG + NBK, 256, 0, stream>>>(
      x, nullptr, w0t, as0, ad0, hfeat, es, ed, NN, packed, gcursor, rowinfo, csr);
  aggregate_kernel<false><<<(NN * 64 + 255) / 256, 256, 0, stream>>>(
      (const uint4*)hfeat, es, ed, rowinfo, csr, b0, h1b, NN,
      nullptr, nullptr, nullptr, nullptr);

  // layer 2: gemm + aggregate with fused classifier head (final_kernel removed)
  gemm_att_kernel<<<NG, 256, 0, stream>>>(
      nullptr, h1b, w1t, as1, ad1, hfeat, es, ed, NN, packed, gcursor, rowinfo, csr);
  aggregate_kernel<true><<<(NN * 64 + 255) / 256, 256, 0, stream>>>(
      (const uint4*)hfeat, es, ed, rowinfo, csr, b1, nullptr, NN,
      (const uint4*)h1b, lwt, lb, out);
}

// Round 7
// 231.758 us; speedup vs baseline: 1.0487x; 1.0487x over previous
//
#include <hip/hip_runtime.h>
#include <hip/hip_fp16.h>
#include <math.h>

#define NN 50000
#define E0 800000
#define ET 850000
#define NBK 196  // CSR buckets = ceil(NN/256), 256 nodes each
#define TILE 4096
#define NTILES 208  // ceil(ET/TILE)
#define CAP 8192    // per-bucket region (packed & padded csr)

typedef unsigned int uint32;
typedef unsigned short u16;
typedef __attribute__((ext_vector_type(8))) _Float16 f16x8;  // 8 f16 = 4 VGPRs
typedef __attribute__((ext_vector_type(4))) float f32x4;

__device__ __forceinline__ u16 f2h(float f) {
  return __half_as_ushort(__float2half(f));  // RNE
}
__device__ __forceinline__ float h2f(u16 u) {
  return __half2float(__ushort_as_half(u));
}

// 256-thread inclusive scan: wave-shuffle (no barriers) + 4-entry wave combine.
// Replaces 8-step Hillis-Steele LDS scan (16 syncthreads -> 1).
__device__ __forceinline__ int block_incl_scan(int v, int tid, int* wsum) {
  const int lane = tid & 63, wid = tid >> 6;
  int val = v;
#pragma unroll
  for (int off = 1; off < 64; off <<= 1) {
    int t = __shfl_up(val, off);
    if (lane >= off) val += t;
  }
  if (lane == 63) wsum[wid] = val;
  __syncthreads();
  int wofs = 0;
#pragma unroll
  for (int w = 0; w < 4; ++w) wofs += (w < wid) ? wsum[w] : 0;
  return val + wofs;
}

// ---- fused: CSR partition (blocks 0..NTILES-1) + W/lw transposes (3 blocks) ----
// Edge loads vectorized int4: E0 and ET are multiples of 4 -> 4-edge chunks are
// uniformly normal / self-loop / invalid (no straddle cases).
__global__ __launch_bounds__(256) void partition_prep_kernel(
    const int* __restrict__ ei, int* __restrict__ gcursor, uint32* __restrict__ packed,
    const float* __restrict__ W0, const float* __restrict__ W1,
    const float* __restrict__ lw,
    u16* __restrict__ w0t, u16* __restrict__ w1t, u16* __restrict__ lwt)
{
  __shared__ __align__(16) char smem[23872];
  const int b = blockIdx.x;
  const int tid = threadIdx.x;
  if (b < NTILES) {
    int* hist  = (int*)smem;               // 1024 (256 ints)
    int* scanb = (int*)(smem + 1024);      // 1024
    int* gofs  = (int*)(smem + 2048);      // 1024
    int* wsum  = (int*)(smem + 3072);      // 16
    uint32* shuf = (uint32*)(smem + 3088); // 16384
    unsigned char* sbkt = (unsigned char*)(smem + 19472);  // 4096
    const int t0 = b * TILE;
    hist[tid] = 0;
    __syncthreads();
    int myb[16]; int myr[16]; uint32 mypk[16];
#pragma unroll
    for (int it = 0; it < 4; ++it) {
      const int q = it * 256 + tid;   // 4-edge chunk index within tile
      const int e4 = t0 + q * 4;      // first edge of chunk (multiple of 4)
      const bool valid = (e4 < ET);
      int sa[4], da[4];
      if (valid) {
        if (e4 + 3 < E0) {   // entirely normal edges (clean split: E0 % 4 == 0)
          int4 sv = *(const int4*)&ei[e4];
          int4 dv = *(const int4*)&ei[E0 + e4];
          sa[0] = sv.x; sa[1] = sv.y; sa[2] = sv.z; sa[3] = sv.w;
          da[0] = dv.x; da[1] = dv.y; da[2] = dv.z; da[3] = dv.w;
        } else {             // entirely self-loops (ET % 4 == 0 -> no partial tail)
#pragma unroll
          for (int u = 0; u < 4; ++u) { sa[u] = e4 - E0 + u; da[u] = sa[u]; }
        }
      }
#pragma unroll
      for (int u = 0; u < 4; ++u) {
        const int i = it * 4 + u;
        myb[i] = -1;
        if (valid) {
          const int src = sa[u], dst = da[u];
          myb[i] = dst >> 8;
          mypk[i] = ((uint32)(dst & 255) << 16) | (uint32)src;
          myr[i] = atomicAdd(&hist[myb[i]], 1);
        }
      }
    }
    __syncthreads();
    const int v = (tid < NBK) ? hist[tid] : 0;
    const int incl = block_incl_scan(v, tid, wsum);
    if (tid < NBK) {
      scanb[tid] = incl - v;
      gofs[tid] = (v > 0) ? atomicAdd(&gcursor[tid], v) : 0;
    }
    __syncthreads();
#pragma unroll
    for (int i = 0; i < 16; ++i) {
      if (myb[i] >= 0) {
        int slot = scanb[myb[i]] + myr[i];
        shuf[slot] = mypk[i];
        sbkt[slot] = (unsigned char)myb[i];
      }
    }
    __syncthreads();
    const int tcount = (t0 + TILE <= ET) ? TILE : (ET - t0);
    for (int i = tid; i < tcount; i += 256) {
      int bb = sbkt[i];
      packed[(size_t)bb * CAP + gofs[bb] + (i - scanb[bb])] = shuf[i];
    }
  } else if (b < NTILES + 2) {
    const float* W = (b == NTILES) ? W0 : W1;
    u16* Wt = (b == NTILES) ? w0t : w1t;
    float (*tile)[129] = (float(*)[129])smem;   // 16.5 KB overlay
    for (int k0 = 0; k0 < 128; k0 += 32) {
      __syncthreads();
#pragma unroll
      for (int it = 0; it < 4; ++it) {
        int q = tid + it * 256;
        int kk = q >> 5, n4 = (q & 31) * 4;
        float4 v = *(const float4*)&W[(k0 + kk) * 128 + n4];
        tile[kk][n4 + 0] = v.x; tile[kk][n4 + 1] = v.y;
        tile[kk][n4 + 2] = v.z; tile[kk][n4 + 3] = v.w;
      }
      __syncthreads();
      int n = tid >> 1, h = (tid & 1) * 16;
      __align__(16) u16 tmp[16];
#pragma unroll
      for (int j = 0; j < 16; ++j) tmp[j] = f2h(tile[h + j][n]);
      *(uint4*)&Wt[n * 128 + k0 + h] = *(uint4*)&tmp[0];
      *(uint4*)&Wt[n * 128 + k0 + h + 8] = *(uint4*)&tmp[8];
    }
  } else {
    for (int idx = tid; idx < 48 * 256; idx += 256) {
      int j = idx >> 8, k = idx & 255;
      lwt[idx] = (j < 40) ? f2h(lw[k * 40 + j]) : (u16)0;
    }
  }
}

// Pass 2 body: per bucket, padded local CSR in LDS (sentinel = NN), u16 csr,
// packed-u32 coalesced writes. Fused into layer-1 gemm dispatch (independent work).
__device__ __forceinline__ void build_body(
    char* smem, int b,
    const uint32* __restrict__ packed, const int* __restrict__ gcursor,
    int2* __restrict__ rowinfo, u16* __restrict__ csr_src)
{
  int* h      = (int*)smem;            // 1024
  int* sc     = (int*)(smem + 1024);   // 1024
  int* cur    = (int*)(smem + 2048);   // 1024
  int* wsum   = (int*)(smem + 3072);   // 16
  int* ptot_p = (int*)(smem + 3088);   // 16 (pad)
  u16* simg   = (u16*)(smem + 3104);   // 16384
  const int tid = threadIdx.x;
  const int cnt = gcursor[b];
  const uint32* pk = packed + (size_t)b * CAP;
  h[tid] = 0;
  cur[tid] = 0;
  __syncthreads();
  for (int i = tid; i < cnt; i += 256) atomicAdd(&h[(pk[i] >> 16) & 255], 1);
  __syncthreads();
  const int pd = (h[tid] + 7) & ~7;   // pad to multiple of 8
  const int incl = block_incl_scan(pd, tid, wsum);
  sc[tid] = incl - pd;
  if (tid == 255) *ptot_p = incl;
  __syncthreads();
  const int ptot = *ptot_p;
  for (int i = tid; i < ptot; i += 256) simg[i] = (u16)NN;   // sentinel fill
  __syncthreads();
  for (int i = tid; i < cnt; i += 256) {
    uint32 p = pk[i];
    int dl = (p >> 16) & 255;
    int r = atomicAdd(&cur[dl], 1);
    simg[sc[dl] + r] = (u16)(p & 0xFFFFu);
  }
  __syncthreads();
  int n = b * 256 + tid;
  if (n < NN) rowinfo[n] = make_int2(b * CAP + sc[tid], pd);
  // ptot is a multiple of 8 -> pair-packed u32 stores cover it exactly
  uint32* dst = (uint32*)(csr_src + (size_t)b * CAP);
  const uint32* sim32 = (const uint32*)simg;
  for (int i = tid; i < (ptot >> 1); i += 256) dst[i] = sim32[i];
}

// ---------------- MFMA GEMM (X @ W) + attention logits, f16 ----------------
// Xf != nullptr: layer 1, read f32 input and convert in-register (RNE, identical
// to a pre-converted xb). Xh != nullptr: layer 2, read f16 features.
// Blocks beyond the gemm grid run build_body (layer-1 dispatch only).
__global__ __launch_bounds__(256) void gemm_att_kernel(
    const float* __restrict__ Xf, const u16* __restrict__ Xh,
    const u16* __restrict__ Wt,
    const float* __restrict__ avs, const float* __restrict__ avd,
    u16* __restrict__ hfeat, float* __restrict__ es, float* __restrict__ ed,
    int nnodes,
    const uint32* __restrict__ packed, const int* __restrict__ gcursor,
    int2* __restrict__ rowinfo, u16* __restrict__ csr_src)
{
  __shared__ __align__(16) char smem[20608];  // max(gemm 18944, build 19488)
  const int ngemm = (nnodes + 63) >> 6;
  if ((int)blockIdx.x >= ngemm) {
    build_body(smem, (int)blockIdx.x - ngemm, packed, gcursor, rowinfo, csr_src);
    return;
  }
  u16* hout   = (u16*)smem;                 // 64*136*2 = 17408
  float* es_s = (float*)(smem + 17408);     // [2][64] = 512
  float* ed_s = (float*)(smem + 17920);     // [2][64] = 512
  const int tid = threadIdx.x;
  const int wid = tid >> 6, lane = tid & 63;
  const int quad = lane >> 4, lc = lane & 15;
  const int n0 = blockIdx.x * 64;
  if (blockIdx.x == 0 && tid < 2) es[2 * NN + tid] = -1e30f;  // sentinel logits -> w=0

  const int arow = wid * 16 + lc;
  const int rrow = min(n0 + arow, nnodes - 1);  // clamp tail (output guarded)

  f32x4 acc[8];
#pragma unroll
  for (int t = 0; t < 8; ++t) acc[t] = (f32x4){0.f, 0.f, 0.f, 0.f};
#pragma unroll
  for (int ks = 0; ks < 4; ++ks) {
    const int k0 = ks * 32 + quad * 8;
    f16x8 a;
    if (Xf) {
      const float4* xr = (const float4*)&Xf[(size_t)rrow * 128 + k0];
      float4 v0 = xr[0], v1 = xr[1];
      a[0] = (_Float16)v0.x; a[1] = (_Float16)v0.y;
      a[2] = (_Float16)v0.z; a[3] = (_Float16)v0.w;
      a[4] = (_Float16)v1.x; a[5] = (_Float16)v1.y;
      a[6] = (_Float16)v1.z; a[7] = (_Float16)v1.w;
    } else {
      a = *(const f16x8*)&Xh[(size_t)rrow * 128 + k0];
    }
#pragma unroll
    for (int t = 0; t < 8; ++t) {
      f16x8 bfr = *(const f16x8*)&Wt[(t * 16 + lc) * 128 + k0];  // L2-resident
      acc[t] = __builtin_amdgcn_mfma_f32_16x16x32_f16(a, bfr, acc[t], 0, 0, 0);
    }
  }

  // attention partials: quad-local shuffle reduction (single writer, no atomics)
  float av_s[8], av_d[8];
#pragma unroll
  for (int t = 0; t < 8; ++t) { av_s[t] = avs[t * 16 + lc]; av_d[t] = avd[t * 16 + lc]; }
#pragma unroll
  for (int r = 0; r < 4; ++r) {
    float s0 = 0.f, s1 = 0.f, d0 = 0.f, d1 = 0.f;
#pragma unroll
    for (int t = 0; t < 4; ++t) { s0 += acc[t][r] * av_s[t]; d0 += acc[t][r] * av_d[t]; }
#pragma unroll
    for (int t = 4; t < 8; ++t) { s1 += acc[t][r] * av_s[t]; d1 += acc[t][r] * av_d[t]; }
#pragma unroll
    for (int m = 1; m < 16; m <<= 1) {
      s0 += __shfl_xor(s0, m); s1 += __shfl_xor(s1, m);
      d0 += __shfl_xor(d0, m); d1 += __shfl_xor(d1, m);
    }
    if (lc == 0) {
      int row = wid * 16 + quad * 4 + r;
      es_s[row] = s0; es_s[64 + row] = s1;
      ed_s[row] = d0; ed_s[64 + row] = d1;
    }
  }
  // f16 output roundtrip for coalesced writeback
#pragma unroll
  for (int t = 0; t < 8; ++t)
#pragma unroll
    for (int r = 0; r < 4; ++r)
      hout[(wid * 16 + quad * 4 + r) * 136 + t * 16 + lc] = f2h(acc[t][r]);
  __syncthreads();
#pragma unroll
  for (int it = 0; it < 4; ++it) {
    int g = tid + it * 256;
    int r = g >> 4, c8 = (g & 15) * 8;
    if (n0 + r < nnodes)
      *(uint4*)&hfeat[(size_t)(n0 + r) * 128 + c8] = *(const uint4*)&hout[r * 136 + c8];
  }
  if (tid < 64) {
    int n = n0 + tid;
    if (n < nnodes) {
      es[n * 2 + 0] = es_s[tid];      es[n * 2 + 1] = es_s[64 + tid];
      ed[n * 2 + 0] = ed_s[tid];      ed[n * 2 + 1] = ed_s[64 + tid];
    }
  }
}

// ---------------- aggregation: one wave per node, 8 edges/iter ----------------
// 256-thread blocks (4 waves): ~20 waves/CU at this VGPR level (1024-thread
// blocks quantize occupancy down to 16 waves/CU -> measured regression R4;
// in-wave fused head -> measured regression R6, agg2 42->68 us).
// Deep pipeline: indices, weights AND feature rows of chunk c+1 are issued
// before the FMA chain consumes chunk c.
__global__ __launch_bounds__(256) void aggregate_kernel(
    const uint4* __restrict__ hfeat4, const float* __restrict__ es, const float* __restrict__ ed,
    const int2* __restrict__ rowinfo, const u16* __restrict__ csr_src,
    const float* __restrict__ bias, u16* __restrict__ out, int nnodes)
{
  int n = (blockIdx.x * blockDim.x + threadIdx.x) >> 6;
  int lane = threadIdx.x & 63;
  if (n >= nnodes) return;
  const int eg = lane >> 4;
  const int fl = lane & 15;
  const int hd = (fl >= 8) ? 1 : 0;
  const int2 ri = rowinfo[n];
  const int nch = ri.y >> 3;
  const int j0 = ri.x + eg;
  const float edn = ed[n * 2 + hd];

  float acc[8];
#pragma unroll
  for (int t = 0; t < 8; ++t) acc[t] = 0.f;
  float den = 0.f;

  // prologue: chunk 0 indices, weights, feature rows
  int iA0 = csr_src[j0], iA1 = csr_src[j0 + 4];
  float e0 = es[iA0 * 2 + hd] + edn; e0 = fmaxf(e0, 0.2f * e0);
  float e1 = es[iA1 * 2 + hd] + edn; e1 = fmaxf(e1, 0.2f * e1);
  float wA0 = __expf(e0), wA1 = __expf(e1);
  uint4 hA0 = hfeat4[(size_t)iA0 * 16 + fl];
  uint4 hA1 = hfeat4[(size_t)iA1 * 16 + fl];

  for (int c = 0;;) {
    const bool more = (c + 1 < nch);
    float wB0 = 0.f, wB1 = 0.f; uint4 hB0, hB1;
    if (more) {
      const int jb = j0 + (c + 1) * 8;
      int iB0 = csr_src[jb], iB1 = csr_src[jb + 4];
      float f0 = es[iB0 * 2 + hd] + edn; f0 = fmaxf(f0, 0.2f * f0);
      float f1 = es[iB1 * 2 + hd] + edn; f1 = fmaxf(f1, 0.2f * f1);
      wB0 = __expf(f0); wB1 = __expf(f1);
      hB0 = hfeat4[(size_t)iB0 * 16 + fl];   // issued before consuming hA*
      hB1 = hfeat4[(size_t)iB1 * 16 + fl];
    }
    // f16 unpack folds into v_fma_mix_f32 (fp32 acc, f16 src via op_sel)
    acc[0] = fmaf(wA0, h2f((u16)(hA0.x & 0xFFFFu)), acc[0]);
    acc[1] = fmaf(wA0, h2f((u16)(hA0.x >> 16)),     acc[1]);
    acc[2] = fmaf(wA0, h2f((u16)(hA0.y & 0xFFFFu)), acc[2]);
    acc[3] = fmaf(wA0, h2f((u16)(hA0.y >> 16)),     acc[3]);
    acc[4] = fmaf(wA0, h2f((u16)(hA0.z & 0xFFFFu)), acc[4]);
    acc[5] = fmaf(wA0, h2f((u16)(hA0.z >> 16)),     acc[5]);
    acc[6] = fmaf(wA0, h2f((u16)(hA0.w & 0xFFFFu)), acc[6]);
    acc[7] = fmaf(wA0, h2f((u16)(hA0.w >> 16)),     acc[7]);
    acc[0] = fmaf(wA1, h2f((u16)(hA1.x & 0xFFFFu)), acc[0]);
    acc[1] = fmaf(wA1, h2f((u16)(hA1.x >> 16)),     acc[1]);
    acc[2] = fmaf(wA1, h2f((u16)(hA1.y & 0xFFFFu)), acc[2]);
    acc[3] = fmaf(wA1, h2f((u16)(hA1.y >> 16)),     acc[3]);
    acc[4] = fmaf(wA1, h2f((u16)(hA1.z & 0xFFFFu)), acc[4]);
    acc[5] = fmaf(wA1, h2f((u16)(hA1.z >> 16)),     acc[5]);
    acc[6] = fmaf(wA1, h2f((u16)(hA1.w & 0xFFFFu)), acc[6]);
    acc[7] = fmaf(wA1, h2f((u16)(hA1.w >> 16)),     acc[7]);
    den += wA0 + wA1;
    if (!more) break;
    wA0 = wB0; wA1 = wB1; hA0 = hB0; hA1 = hB1;
    ++c;
  }

#pragma unroll
  for (int t = 0; t < 8; ++t) {
    acc[t] += __shfl_xor(acc[t], 16);
    acc[t] += __shfl_xor(acc[t], 32);
  }
  den += __shfl_xor(den, 16);
  den += __shfl_xor(den, 32);

  if (eg == 0) {
    float inv = 1.f / den;
    float4 b0 = *(const float4*)&bias[fl * 8];
    float4 b1 = *(const float4*)&bias[fl * 8 + 4];
    float bv[8] = {b0.x, b0.y, b0.z, b0.w, b1.x, b1.y, b1.z, b1.w};
    u16 pk[8];
#pragma unroll
    for (int t = 0; t < 8; ++t) {
      float v = acc[t] * inv + bv[t];
      v = (v > 0.f) ? v : (__expf(v) - 1.f);  // ELU
      pk[t] = f2h(v);
    }
    uint4 o;
    o.x = (uint32)pk[0] | ((uint32)pk[1] << 16);
    o.y = (uint32)pk[2] | ((uint32)pk[3] << 16);
    o.z = (uint32)pk[4] | ((uint32)pk[5] << 16);
    o.w = (uint32)pk[6] | ((uint32)pk[7] << 16);
    ((uint4*)out)[(size_t)n * 16 + fl] = o;
  }
}

// ---------------- final: MFMA [64x256] @ [256x48] + log_softmax, zero LDS ----------------
__global__ __launch_bounds__(256) void final_kernel(
    const u16* __restrict__ h1b, const u16* __restrict__ h2b,
    const u16* __restrict__ lwt, const float* __restrict__ lb,
    float* __restrict__ out, int nnodes)
{
  const int tid = threadIdx.x;
  const int wid = tid >> 6, lane = tid & 63;
  const int quad = lane >> 4, lc = lane & 15;
  const int n0 = blockIdx.x * 64;
  const int arow = wid * 16 + lc;
  const int rrow = min(n0 + arow, nnodes - 1);

  f32x4 acc[3];
#pragma unroll
  for (int t = 0; t < 3; ++t) acc[t] = (f32x4){0.f, 0.f, 0.f, 0.f};
#pragma unroll
  for (int ks = 0; ks < 8; ++ks) {
    const u16* hsrc = (ks < 4) ? h1b : h2b;
    const int k0 = (ks & 3) * 32 + quad * 8;
    const int kl = ks * 32 + quad * 8;
    f16x8 a = *(const f16x8*)&hsrc[(size_t)rrow * 128 + k0];
#pragma unroll
    for (int t = 0; t < 3; ++t) {
      f16x8 b = *(const f16x8*)&lwt[(t * 16 + lc) * 256 + kl];  // L2-resident
      acc[t] = __builtin_amdgcn_mfma_f32_16x16x32_f16(a, b, acc[t], 0, 0, 0);
    }
  }

  float bv[3];
  bool valid[3];
#pragma unroll
  for (int t = 0; t < 3; ++t) {
    int col = t * 16 + lc;
    valid[t] = (col < 40);
    bv[t] = valid[t] ? lb[col] : 0.f;
  }
#pragma unroll
  for (int r = 0; r < 4; ++r) {
    int row = wid * 16 + quad * 4 + r;
    int n = n0 + row;
    float v[3];
    float mx = -INFINITY;
#pragma unroll
    for (int t = 0; t < 3; ++t) {
      v[t] = acc[t][r] + bv[t];
      if (valid[t]) mx = fmaxf(mx, v[t]);
    }
    mx = fmaxf(mx, __shfl_xor(mx, 1));
    mx = fmaxf(mx, __shfl_xor(mx, 2));
    mx = fmaxf(mx, __shfl_xor(mx, 4));
    mx = fmaxf(mx, __shfl_xor(mx, 8));
    float s = 0.f;
#pragma unroll
    for (int t = 0; t < 3; ++t) if (valid[t]) s += __expf(v[t] - mx);
    s += __shfl_xor(s, 1);
    s += __shfl_xor(s, 2);
    s += __shfl_xor(s, 4);
    s += __shfl_xor(s, 8);
    float lg = mx + __logf(s);
    if (n < nnodes) {
#pragma unroll
      for (int t = 0; t < 3; ++t)
        if (valid[t]) out[(size_t)n * 40 + t * 16 + lc] = v[t] - lg;
    }
  }
}

// ---------------- launch ----------------

extern "C" void kernel_launch(void* const* d_in, const int* in_sizes, int n_in,
                              void* d_out, int out_size, void* d_ws, size_t ws_size,
                              hipStream_t stream) {
  const float* x   = (const float*)d_in[0];
  const int*   ei  = (const int*)d_in[1];
  const float* W0  = (const float*)d_in[2];
  const float* as0 = (const float*)d_in[3];
  const float* ad0 = (const float*)d_in[4];
  const float* b0  = (const float*)d_in[5];
  const float* W1  = (const float*)d_in[6];
  const float* as1 = (const float*)d_in[7];
  const float* ad1 = (const float*)d_in[8];
  const float* b1  = (const float*)d_in[9];
  const float* lw  = (const float*)d_in[10];
  const float* lb  = (const float*)d_in[11];
  float* out = (float*)d_out;

  char* p = (char*)d_ws;
  auto carve = [&](size_t bytes) { char* r = p; p += (bytes + 255) & ~(size_t)255; return r; };
  u16* w0t    = (u16*)carve(128 * 128 * 2);
  u16* w1t    = (u16*)carve(128 * 128 * 2);
  u16* lwt    = (u16*)carve(48 * 256 * 2);
  u16* hfeat  = (u16*)carve((size_t)(NN + 1) * 128 * 2);  // +1 sentinel row
  u16* h1b    = (u16*)carve((size_t)NN * 128 * 2);
  u16* h2b    = (u16*)carve((size_t)NN * 128 * 2);
  float* es   = (float*)carve((size_t)(NN + 1) * 2 * 4);  // +sentinel logits
  float* ed   = (float*)carve((size_t)NN * 2 * 4);
  int2* rowinfo = (int2*)carve((size_t)NN * 8);
  u16* csr    = (u16*)carve((size_t)NBK * CAP * 2);       // u16 node ids (NN < 65536)
  uint32* packed = (uint32*)carve((size_t)NBK * CAP * 4);
  int* gcursor = (int*)carve(NBK * 4);

  hipMemsetAsync(gcursor, 0, NBK * 4, stream);

  const int NG = (NN + 63) / 64;  // 782

  // CSR partition + weight transposes (211 blocks)
  partition_prep_kernel<<<NTILES + 3, 256, 0, stream>>>(
      ei, gcursor, packed, W0, W1, lw, w0t, w1t, lwt);

  // layer 1: gemm (f32 input, in-register f16 convert) + fused CSR build blocks
  gemm_att_kernel<<<NG + NBK, 256, 0, stream>>>(
      x, nullptr, w0t, as0, ad0, hfeat, es, ed, NN, packed, gcursor, rowinfo, csr);
  aggregate_kernel<<<(NN * 64 + 255) / 256, 256, 0, stream>>>(
      (const uint4*)hfeat, es, ed, rowinfo, csr, b0, h1b, NN);

  // layer 2
  gemm_att_kernel<<<NG, 256, 0, stream>>>(
      nullptr, h1b, w1t, as1, ad1, hfeat, es, ed, NN, packed, gcursor, rowinfo, csr);
  aggregate_kernel<<<(NN * 64 + 255) / 256, 256, 0, stream>>>(
      (const uint4*)hfeat, es, ed, rowinfo, csr, b1, h2b, NN);

  // head
  final_kernel<<<NG, 256, 0, stream>>>(h1b, h2b, lwt, lb, out, NN);
}